// Round 5
// baseline (549.133 us; speedup 1.0000x reference)
//
#include <hip/hip_runtime.h>
#include <cstdint>

#define N_ITEMS 100000
#define B_USERS 1024

constexpr int RB = 8;   // rows (users) per block
constexpr int CS = 8;   // column splits across N
constexpr int NT = 256; // threads per block

typedef float floatx4 __attribute__((ext_vector_type(4))); // native vec for nontemporal builtin

// ---------------- Kernel 1: per-item score s[j] ----------------
// c = relu(gamma[j,:] @ Wa + ba0); s[j] = (c @ h + ba1) * log2(e)
// (log2(e) folded in so the main kernel can use the HW exp2 unit directly)
__global__ __launch_bounds__(256) void compute_s(
    const float* __restrict__ gamma, const float* __restrict__ Wa,
    const float* __restrict__ ba0, const float* __restrict__ ba1,
    const float* __restrict__ h, float* __restrict__ s_out)
{
    int j = blockIdx.x * 256 + threadIdx.x;
    if (j >= N_ITEMS) return;
    const float4* gp = reinterpret_cast<const float4*>(gamma + (size_t)j * 8);
    float4 g0 = gp[0], g1 = gp[1];
    float g[8] = {g0.x, g0.y, g0.z, g0.w, g1.x, g1.y, g1.z, g1.w};
    float s = ba1[0];
#pragma unroll
    for (int d = 0; d < 8; ++d) {
        float c = ba0[d];
#pragma unroll
        for (int k = 0; k < 8; ++k) c += g[k] * Wa[k * 8 + d];
        c = fmaxf(c, 0.f);
        s += c * h[d];
    }
    s_out[j] = s * 1.4426950408889634f; // * log2(e)
}

// ---------------- Kernel 2: fused exp + weighted reduction ----------------
// For each row b: sumE_b = sum_j exp(in[b,j]*s[j]); acc_b[d] = sum_j e * gamma[j,d]
// Block (rg, cs): rows rg*RB..+RB-1, column stripe cs. Writes partial[cs][row][9].
__global__ __launch_bounds__(256) void fused_main(
    const float* __restrict__ inputs, const float* __restrict__ gamma,
    const float* __restrict__ s, float* __restrict__ partial)
{
    const int tid = threadIdx.x;
    const int rg = blockIdx.x;   // 0..B/RB-1
    const int cs = blockIdx.y;   // 0..CS-1
    const int row0 = rg * RB;
    const int nf4 = N_ITEMS / 4; // 25000 (exact)

    const floatx4* in4 = reinterpret_cast<const floatx4*>(inputs);
    const float4*  g4  = reinterpret_cast<const float4*>(gamma);
    const float4*  s4p = reinterpret_cast<const float4*>(s);

    float acc[RB][8];
    float sumE[RB];
#pragma unroll
    for (int r = 0; r < RB; ++r) {
        sumE[r] = 0.f;
#pragma unroll
        for (int d = 0; d < 8; ++d) acc[r][d] = 0.f;
    }

    for (int i = cs * NT + tid; i < nf4; i += CS * NT) {
        float4 sv4 = s4p[i];
        float sv[4] = {sv4.x, sv4.y, sv4.z, sv4.w};
        // gamma rows j0..j0+3 (j0 = 4*i): 8 float4s, coalesced across the wave
        float gg[32];
#pragma unroll
        for (int q = 0; q < 8; ++q) {
            float4 t = g4[(size_t)i * 8 + q];
            gg[4 * q + 0] = t.x; gg[4 * q + 1] = t.y;
            gg[4 * q + 2] = t.z; gg[4 * q + 3] = t.w;
        }
#pragma unroll
        for (int r = 0; r < RB; ++r) {
            // inputs are streamed exactly once: nontemporal to keep gamma in L2
            floatx4 x4 = __builtin_nontemporal_load(&in4[(size_t)(row0 + r) * nf4 + i]);
            float xv[4] = {x4.x, x4.y, x4.z, x4.w};
#pragma unroll
            for (int jj = 0; jj < 4; ++jj) {
                // s already carries log2(e): exp(x*s_orig) == exp2(x*s)
                float e = exp2f(xv[jj] * sv[jj]);
                sumE[r] += e;
#pragma unroll
                for (int d = 0; d < 8; ++d)
                    acc[r][d] += e * gg[8 * jj + d];
            }
        }
    }

    // ---- wave (64-lane) butterfly reduce of 9 values per row ----
#pragma unroll
    for (int r = 0; r < RB; ++r) {
#pragma unroll
        for (int m = 32; m >= 1; m >>= 1) sumE[r] += __shfl_xor(sumE[r], m);
#pragma unroll
        for (int d = 0; d < 8; ++d) {
#pragma unroll
            for (int m = 32; m >= 1; m >>= 1) acc[r][d] += __shfl_xor(acc[r][d], m);
        }
    }

    // ---- cross-wave reduce via LDS (4 waves) ----
    __shared__ float lds[NT / 64][RB][9];
    const int wave = tid >> 6;
    const int lane = tid & 63;
    if (lane == 0) {
#pragma unroll
        for (int r = 0; r < RB; ++r) {
            lds[wave][r][0] = sumE[r];
#pragma unroll
            for (int d = 0; d < 8; ++d) lds[wave][r][1 + d] = acc[r][d];
        }
    }
    __syncthreads();
    if (tid < RB * 9) {
        int r = tid / 9, c = tid % 9;
        float v = lds[0][r][c] + lds[1][r][c] + lds[2][r][c] + lds[3][r][c];
        partial[((size_t)cs * B_USERS + (row0 + r)) * 9 + c] = v;
    }
}

// ---------------- Kernel 3: finalize out[b,d] = num/den ----------------
__global__ __launch_bounds__(256) void finalize(
    const float* __restrict__ partial, float* __restrict__ out)
{
    int t = blockIdx.x * 256 + threadIdx.x;
    if (t >= B_USERS * 8) return;
    int b = t >> 3, d = t & 7;
    float den = 0.f, num = 0.f;
#pragma unroll
    for (int cs = 0; cs < CS; ++cs) {
        den += partial[((size_t)cs * B_USERS + b) * 9 + 0];
        num += partial[((size_t)cs * B_USERS + b) * 9 + 1 + d];
    }
    out[t] = num / den;
}

extern "C" void kernel_launch(void* const* d_in, const int* in_sizes, int n_in,
                              void* d_out, int out_size, void* d_ws, size_t ws_size,
                              hipStream_t stream) {
    const float* inputs = (const float*)d_in[0];
    const float* gamma  = (const float*)d_in[1];
    const float* Wa     = (const float*)d_in[2];
    const float* ba0    = (const float*)d_in[3];
    const float* ba1    = (const float*)d_in[4];
    const float* h      = (const float*)d_in[5];
    float* out = (float*)d_out;

    float* s_ws    = (float*)d_ws;          // N_ITEMS floats (400000 B, 16B-aligned)
    float* partial = s_ws + N_ITEMS;        // CS*B*9 floats (~295 KB)

    compute_s<<<(N_ITEMS + 255) / 256, 256, 0, stream>>>(gamma, Wa, ba0, ba1, h, s_ws);
    dim3 grid(B_USERS / RB, CS);
    fused_main<<<grid, NT, 0, stream>>>(inputs, gamma, s_ws, partial);
    finalize<<<(B_USERS * 8 + 255) / 256, 256, 0, stream>>>(partial, out);
}

// Round 6
// 548.651 us; speedup vs baseline: 1.0009x; 1.0009x over previous
//
#include <hip/hip_runtime.h>
#include <cstdint>

#define N_ITEMS 100000
#define B_USERS 1024

constexpr int RB = 8;   // rows (users) per block
constexpr int CS = 8;   // column splits across N
constexpr int NT = 256; // threads per block

typedef float floatx4 __attribute__((ext_vector_type(4))); // native vec for nontemporal builtin

// ---------------- Kernel 1: per-item score s[j] ----------------
// c = relu(gamma[j,:] @ Wa + ba0); s[j] = (c @ h + ba1) * log2(e)
// (log2(e) folded in so the main kernel can use the HW exp2 unit directly)
__global__ __launch_bounds__(256) void compute_s(
    const float* __restrict__ gamma, const float* __restrict__ Wa,
    const float* __restrict__ ba0, const float* __restrict__ ba1,
    const float* __restrict__ h, float* __restrict__ s_out)
{
    int j = blockIdx.x * 256 + threadIdx.x;
    if (j >= N_ITEMS) return;
    const float4* gp = reinterpret_cast<const float4*>(gamma + (size_t)j * 8);
    float4 g0 = gp[0], g1 = gp[1];
    float g[8] = {g0.x, g0.y, g0.z, g0.w, g1.x, g1.y, g1.z, g1.w};
    float s = ba1[0];
#pragma unroll
    for (int d = 0; d < 8; ++d) {
        float c = ba0[d];
#pragma unroll
        for (int k = 0; k < 8; ++k) c += g[k] * Wa[k * 8 + d];
        c = fmaxf(c, 0.f);
        s += c * h[d];
    }
    s_out[j] = s * 1.4426950408889634f; // * log2(e)
}

// ---------------- Kernel 2: fused exp + weighted reduction ----------------
// For each row b: sumE_b = sum_j exp(in[b,j]*s[j]); acc_b[d] = sum_j e * gamma[j,d]
// Block (rg, cs): rows rg*RB..+RB-1, column stripe cs. Writes partial[cs][row][9].
// Loop body issues all 8 HBM (inputs) loads FIRST for max memory-level
// parallelism, then the (L1/L2-resident) gamma loads, then compute.
__global__ __launch_bounds__(256) void fused_main(
    const float* __restrict__ inputs, const float* __restrict__ gamma,
    const float* __restrict__ s, float* __restrict__ partial)
{
    const int tid = threadIdx.x;
    const int rg = blockIdx.x;   // 0..B/RB-1
    const int cs = blockIdx.y;   // 0..CS-1
    const int row0 = rg * RB;
    const int nf4 = N_ITEMS / 4; // 25000 (exact)

    const floatx4* in4 = reinterpret_cast<const floatx4*>(inputs);
    const float4*  g4  = reinterpret_cast<const float4*>(gamma);
    const float4*  s4p = reinterpret_cast<const float4*>(s);

    float acc[RB][8];
    float sumE[RB];
#pragma unroll
    for (int r = 0; r < RB; ++r) {
        sumE[r] = 0.f;
#pragma unroll
        for (int d = 0; d < 8; ++d) acc[r][d] = 0.f;
    }

    for (int i = cs * NT + tid; i < nf4; i += CS * NT) {
        // ---- 1) issue all HBM streaming loads first (8 rows, nontemporal) ----
        floatx4 xs[RB];
#pragma unroll
        for (int r = 0; r < RB; ++r)
            xs[r] = __builtin_nontemporal_load(&in4[(size_t)(row0 + r) * nf4 + i]);

        // ---- 2) cache-resident loads: s and gamma rows j0..j0+3 ----
        float4 sv4 = s4p[i];
        float sv[4] = {sv4.x, sv4.y, sv4.z, sv4.w};
        float gg[32];
#pragma unroll
        for (int q = 0; q < 8; ++q) {
            float4 t = g4[(size_t)i * 8 + q];
            gg[4 * q + 0] = t.x; gg[4 * q + 1] = t.y;
            gg[4 * q + 2] = t.z; gg[4 * q + 3] = t.w;
        }

        // ---- 3) compute ----
#pragma unroll
        for (int r = 0; r < RB; ++r) {
            float xv[4] = {xs[r].x, xs[r].y, xs[r].z, xs[r].w};
#pragma unroll
            for (int jj = 0; jj < 4; ++jj) {
                // s already carries log2(e): exp(x*s_orig) == exp2(x*s)
                float e = exp2f(xv[jj] * sv[jj]);
                sumE[r] += e;
#pragma unroll
                for (int d = 0; d < 8; ++d)
                    acc[r][d] += e * gg[8 * jj + d];
            }
        }
    }

    // ---- wave (64-lane) butterfly reduce of 9 values per row ----
#pragma unroll
    for (int r = 0; r < RB; ++r) {
#pragma unroll
        for (int m = 32; m >= 1; m >>= 1) sumE[r] += __shfl_xor(sumE[r], m);
#pragma unroll
        for (int d = 0; d < 8; ++d) {
#pragma unroll
            for (int m = 32; m >= 1; m >>= 1) acc[r][d] += __shfl_xor(acc[r][d], m);
        }
    }

    // ---- cross-wave reduce via LDS (4 waves) ----
    __shared__ float lds[NT / 64][RB][9];
    const int wave = tid >> 6;
    const int lane = tid & 63;
    if (lane == 0) {
#pragma unroll
        for (int r = 0; r < RB; ++r) {
            lds[wave][r][0] = sumE[r];
#pragma unroll
            for (int d = 0; d < 8; ++d) lds[wave][r][1 + d] = acc[r][d];
        }
    }
    __syncthreads();
    if (tid < RB * 9) {
        int r = tid / 9, c = tid % 9;
        float v = lds[0][r][c] + lds[1][r][c] + lds[2][r][c] + lds[3][r][c];
        partial[((size_t)cs * B_USERS + (row0 + r)) * 9 + c] = v;
    }
}

// ---------------- Kernel 3: finalize out[b,d] = num/den ----------------
__global__ __launch_bounds__(256) void finalize(
    const float* __restrict__ partial, float* __restrict__ out)
{
    int t = blockIdx.x * 256 + threadIdx.x;
    if (t >= B_USERS * 8) return;
    int b = t >> 3, d = t & 7;
    float den = 0.f, num = 0.f;
#pragma unroll
    for (int cs = 0; cs < CS; ++cs) {
        den += partial[((size_t)cs * B_USERS + b) * 9 + 0];
        num += partial[((size_t)cs * B_USERS + b) * 9 + 1 + d];
    }
    out[t] = num / den;
}

extern "C" void kernel_launch(void* const* d_in, const int* in_sizes, int n_in,
                              void* d_out, int out_size, void* d_ws, size_t ws_size,
                              hipStream_t stream) {
    const float* inputs = (const float*)d_in[0];
    const float* gamma  = (const float*)d_in[1];
    const float* Wa     = (const float*)d_in[2];
    const float* ba0    = (const float*)d_in[3];
    const float* ba1    = (const float*)d_in[4];
    const float* h      = (const float*)d_in[5];
    float* out = (float*)d_out;

    float* s_ws    = (float*)d_ws;          // N_ITEMS floats (400000 B, 16B-aligned)
    float* partial = s_ws + N_ITEMS;        // CS*B*9 floats (~295 KB)

    compute_s<<<(N_ITEMS + 255) / 256, 256, 0, stream>>>(gamma, Wa, ba0, ba1, h, s_ws);
    dim3 grid(B_USERS / RB, CS);
    fused_main<<<grid, NT, 0, stream>>>(inputs, gamma, s_ws, partial);
    finalize<<<(B_USERS * 8 + 255) / 256, 256, 0, stream>>>(partial, out);
}